// Round 5
// baseline (105.685 us; speedup 1.0000x reference)
//
#include <hip/hip_runtime.h>
#include <hip/hip_bf16.h>

#define NSAMP 8192
#define HD 128
#define NC 18
#define SB 8            // samples per block
#define NCOLS 144       // SB*NC
#define KSTR 136        // padded k-stride in shorts (272B rows, 16B-aligned)

typedef __attribute__((ext_vector_type(8))) short bf16x8;
typedef __attribute__((ext_vector_type(4))) float f32x4;
typedef float f2 __attribute__((ext_vector_type(2)));

// Monomial map: 0:1 1:a 2:b 3:c 4:a2 5:ab 6:b2 7:ca 8:cb 9:a3 10:a2b 11:ab2
// 12:b3 13:ca2 14:cb2 15:a4 16:a2b2 17:b4   (a=dx, b=dy, c=dt)

__device__ __forceinline__ unsigned packf2(f2 v) {
    __hip_bfloat162 h = __float22bfloat162_rn(float2{v.x, v.y});
    return *(unsigned*)&h;
}
__device__ __forceinline__ f2 unpk(unsigned r) {
    f2 v;
    v.x = __uint_as_float(r << 16);
    v.y = __uint_as_float(r & 0xffff0000u);
    return v;
}

__device__ __forceinline__ void jmul2(const f2* __restrict__ p,
                                      const f2* __restrict__ q,
                                      f2* __restrict__ r) {
    r[0]  = p[0]*q[0];
    r[1]  = p[0]*q[1]  + p[1]*q[0];
    r[2]  = p[0]*q[2]  + p[2]*q[0];
    r[3]  = p[0]*q[3]  + p[3]*q[0];
    r[4]  = p[0]*q[4]  + p[4]*q[0]  + p[1]*q[1];
    r[5]  = p[0]*q[5]  + p[5]*q[0]  + p[1]*q[2]  + p[2]*q[1];
    r[6]  = p[0]*q[6]  + p[6]*q[0]  + p[2]*q[2];
    r[7]  = p[0]*q[7]  + p[7]*q[0]  + p[1]*q[3]  + p[3]*q[1];
    r[8]  = p[0]*q[8]  + p[8]*q[0]  + p[2]*q[3]  + p[3]*q[2];
    r[9]  = p[0]*q[9]  + p[9]*q[0]  + p[1]*q[4]  + p[4]*q[1];
    r[10] = p[0]*q[10] + p[10]*q[0] + p[1]*q[5]  + p[5]*q[1] + p[2]*q[4] + p[4]*q[2];
    r[11] = p[0]*q[11] + p[11]*q[0] + p[1]*q[6]  + p[6]*q[1] + p[2]*q[5] + p[5]*q[2];
    r[12] = p[0]*q[12] + p[12]*q[0] + p[2]*q[6]  + p[6]*q[2];
    r[13] = p[0]*q[13] + p[13]*q[0] + p[1]*q[7]  + p[7]*q[1] + p[3]*q[4] + p[4]*q[3];
    r[14] = p[0]*q[14] + p[14]*q[0] + p[2]*q[8]  + p[8]*q[2] + p[3]*q[6] + p[6]*q[3];
    r[15] = p[0]*q[15] + p[15]*q[0] + p[1]*q[9]  + p[9]*q[1] + p[4]*q[4];
    r[16] = p[0]*q[16] + p[16]*q[0] + p[1]*q[11] + p[11]*q[1] + p[2]*q[10] + p[10]*q[2]
          + p[4]*q[6]  + p[6]*q[4]  + p[5]*q[5];
    r[17] = p[0]*q[17] + p[17]*q[0] + p[2]*q[12] + p[12]*q[2] + p[6]*q[6];
}

__device__ __forceinline__ void tanh_jet2(const f2* __restrict__ f,
                                          f2* __restrict__ out) {
    f2 y;  y.x = tanhf(f[0].x);  y.y = tanhf(f[0].y);
    const f2 one = {1.0f, 1.0f};
    const f2 s  = one - y*y;
    const f2 t2 = -y*s;
    const f2 t3 = s*(y*y - 0.3333333333333333f);
    const f2 t4 = y*s*(one + one - 3.0f*y*y) * 0.3333333333333333f;
    f2 p[NC], A[NC], B[NC];
    p[0] = (f2)0.0f;
#pragma unroll
    for (int i = 1; i < NC; ++i) p[i] = f[i];
    A[0] = t3;
#pragma unroll
    for (int i = 1; i < NC; ++i) A[i] = t4 * p[i];
    jmul2(p, A, B);  B[0] += t2;
    jmul2(p, B, A);  A[0] += s;
    jmul2(p, A, out); out[0] += y;
}

__global__ __launch_bounds__(512, 4)
void hydro_main(const float* __restrict__ x,
                const float* __restrict__ W1, const float* __restrict__ b1,
                const float* __restrict__ W2, const float* __restrict__ b2,
                const float* __restrict__ W3, const float* __restrict__ b3,
                const float* __restrict__ W4, const float* __restrict__ nu_p,
                float* __restrict__ out) {
    __shared__ __align__(16) unsigned short Hl[NCOLS * KSTR];  // jets/preacts, bf16
    __shared__ float psis[NCOLS];

    const int tid = threadIdx.x;
    const int wv  = tid >> 6;
    const int ln  = tid & 63;
    const int s0  = blockIdx.x * SB;

    // ---- Layer 1: 512 unit-pairs, float2 jets ----
    {
        const int s  = tid >> 6;
        const int jp = tid & 63;
        const float xs = x[3 * (s0 + s) + 0];
        const float ys = x[3 * (s0 + s) + 1];
        const float ts = x[3 * (s0 + s) + 2];
        const int j0 = 2 * jp;
        const f2 wx = *(const f2*)&W1[j0];
        const f2 wy = *(const f2*)&W1[HD + j0];
        const f2 wt = *(const f2*)&W1[2 * HD + j0];
        const f2 bb = *(const f2*)&b1[j0];
        f2 f[NC], h[NC];
#pragma unroll
        for (int c = 0; c < NC; ++c) f[c] = (f2)0.0f;
        f[0] = wx * xs + wy * ys + wt * ts + bb;
        f[1] = wx; f[2] = wy; f[3] = wt;
        tanh_jet2(f, h);
#pragma unroll
        for (int c = 0; c < NC; ++c)
            *(unsigned*)&Hl[(s * NC + c) * KSTR + j0] = packf2(h[c]);
    }
    __syncthreads();

    // ---- Layers 2,3: MFMA GEMM, wave = (m-group of 32, n-half of 5 tiles) ----
    const int half = wv & 1;
    const int ntb  = half * 4;                 // n-tiles ntb..ntb+4 (overlap at 4)
    const int mg   = wv >> 1;                  // m-group 0..3 (rows 32mg..32mg+31)
    const int mr0  = mg * 32 + (ln & 15);      // m-tile 0 row
    const int koff = (ln >> 4) * 8;

#pragma unroll 1
    for (int L = 0; L < 2; ++L) {
        const float* __restrict__ W = L ? W3 : W2;
        f32x4 acc[2][5];
#pragma unroll
        for (int mt = 0; mt < 2; ++mt)
#pragma unroll
            for (int t = 0; t < 5; ++t) acc[mt][t] = (f32x4)0.0f;

#pragma unroll 1
        for (int ks = 0; ks < 4; ++ks) {
            const int kb = ks * 32 + koff;
            union { uint4 u; bf16x8 v; } a0, a1;
            a0.u.x = packf2(f2{W[(kb + 0) * HD + mr0], W[(kb + 1) * HD + mr0]});
            a0.u.y = packf2(f2{W[(kb + 2) * HD + mr0], W[(kb + 3) * HD + mr0]});
            a0.u.z = packf2(f2{W[(kb + 4) * HD + mr0], W[(kb + 5) * HD + mr0]});
            a0.u.w = packf2(f2{W[(kb + 6) * HD + mr0], W[(kb + 7) * HD + mr0]});
            a1.u.x = packf2(f2{W[(kb + 0) * HD + mr0 + 16], W[(kb + 1) * HD + mr0 + 16]});
            a1.u.y = packf2(f2{W[(kb + 2) * HD + mr0 + 16], W[(kb + 3) * HD + mr0 + 16]});
            a1.u.z = packf2(f2{W[(kb + 4) * HD + mr0 + 16], W[(kb + 5) * HD + mr0 + 16]});
            a1.u.w = packf2(f2{W[(kb + 6) * HD + mr0 + 16], W[(kb + 7) * HD + mr0 + 16]});
#pragma unroll
            for (int t = 0; t < 5; ++t) {
                const int n = (ntb + t) * 16 + (ln & 15);
                const bf16x8 Bf = *(const bf16x8*)&Hl[n * KSTR + kb];
                acc[0][t] = __builtin_amdgcn_mfma_f32_16x16x32_bf16(a0.v, Bf, acc[0][t], 0, 0, 0);
                acc[1][t] = __builtin_amdgcn_mfma_f32_16x16x32_bf16(a1.v, Bf, acc[1][t], 0, 0, 0);
            }
        }
        __syncthreads();
        // writeback pre-activations: C[m][n] -> Hl[n][m], bf16
        // (n-halves overlap at nt4: both waves write bitwise-identical data)
#pragma unroll
        for (int t = 0; t < 5; ++t) {
            const int n  = (ntb + t) * 16 + (ln & 15);
            const int m0 = mg * 32 + (ln >> 4) * 4;
            uint2 w0, w1;
            w0.x = packf2(f2{acc[0][t].x, acc[0][t].y});
            w0.y = packf2(f2{acc[0][t].z, acc[0][t].w});
            w1.x = packf2(f2{acc[1][t].x, acc[1][t].y});
            w1.y = packf2(f2{acc[1][t].z, acc[1][t].w});
            *(uint2*)&Hl[n * KSTR + m0]      = w0;
            *(uint2*)&Hl[n * KSTR + m0 + 16] = w1;
        }
        __syncthreads();
        // tanh phase: 256 threads, unit-QUADS (b64 LDS traffic), two f2 jets each
        if (tid < 256) {
            const float* bL = L ? b3 : b2;
            const int s  = tid >> 5;
            const int q  = tid & 31;
            const int j0 = 4 * q;
            f2 fa[NC], fb[NC], ha[NC], hb[NC];
#pragma unroll
            for (int c = 0; c < NC; ++c) {
                const uint2 u = *(const uint2*)&Hl[(s * NC + c) * KSTR + j0];
                fa[c] = unpk(u.x);
                fb[c] = unpk(u.y);
            }
            fa[0] += *(const f2*)&bL[j0];
            fb[0] += *(const f2*)&bL[j0 + 2];
            tanh_jet2(fa, ha);
            tanh_jet2(fb, hb);
#pragma unroll
            for (int c = 0; c < NC; ++c) {
                uint2 w;
                w.x = packf2(ha[c]);
                w.y = packf2(hb[c]);
                *(uint2*)&Hl[(s * NC + c) * KSTR + j0] = w;
            }
        }
        __syncthreads();
    }

    // ---- Layer 4: psi jet coefs = W4 . h3 ----
    if (tid < NCOLS) {
        float acc = 0.0f;
#pragma unroll
        for (int kk = 0; kk < 16; ++kk) {
            const uint4 q = *(const uint4*)&Hl[tid * KSTR + kk * 8];
            const int k = kk * 8;
            const f2 e0 = unpk(q.x), e1 = unpk(q.y), e2 = unpk(q.z), e3 = unpk(q.w);
            acc = fmaf(e0.x, W4[k + 0], acc);
            acc = fmaf(e0.y, W4[k + 1], acc);
            acc = fmaf(e1.x, W4[k + 2], acc);
            acc = fmaf(e1.y, W4[k + 3], acc);
            acc = fmaf(e2.x, W4[k + 4], acc);
            acc = fmaf(e2.y, W4[k + 5], acc);
            acc = fmaf(e3.x, W4[k + 6], acc);
            acc = fmaf(e3.y, W4[k + 7], acc);
        }
        psis[tid] = acc;
    }
    __syncthreads();

    if (tid < SB) {
        const float* p = &psis[tid * NC];
        const float nu = nu_p[0];
        const float u  = p[2];
        const float v  = -p[1];
        const float wx = -(6.0f * p[9]  + 2.0f * p[11]);
        const float wy = -(2.0f * p[10] + 6.0f * p[12]);
        const float wt = -(2.0f * p[13] + 2.0f * p[14]);
        const float lapw = -(24.0f * p[15] + 8.0f * p[16] + 24.0f * p[17]);
        const float nse  = wt + wx * u + wy * v - nu * lapw;
        const int gi = s0 + tid;
        out[2 * gi]         = u;
        out[2 * gi + 1]     = v;
        out[2 * NSAMP + gi] = nse;
    }
}

extern "C" void kernel_launch(void* const* d_in, const int* in_sizes, int n_in,
                              void* d_out, int out_size, void* d_ws, size_t ws_size,
                              hipStream_t stream) {
    const float* x  = (const float*)d_in[0];
    const float* W1 = (const float*)d_in[1];
    const float* b1 = (const float*)d_in[2];
    const float* W2 = (const float*)d_in[3];
    const float* b2 = (const float*)d_in[4];
    const float* W3 = (const float*)d_in[5];
    const float* b3 = (const float*)d_in[6];
    const float* W4 = (const float*)d_in[7];
    const float* nu = (const float*)d_in[9];
    float* out = (float*)d_out;

    hipLaunchKernelGGL(hydro_main, dim3(NSAMP / SB), dim3(512), 0, stream,
                       x, W1, b1, W2, b2, W3, b3, W4, nu, out);
}